// Round 1
// baseline (1177.972 us; speedup 1.0000x reference)
//
#include <hip/hip_runtime.h>

#define F 128
#define F4 32   // floats4 per row
#define TN 64   // nodes per GEMM block

// ---------------- zero workspace ----------------
__global__ void zero_kernel(float4* __restrict__ agg4, float* __restrict__ deg, int n) {
    int i = blockIdx.x * blockDim.x + threadIdx.x;
    int stride = gridDim.x * blockDim.x;
    int total4 = n * F4;
    for (int j = i; j < total4; j += stride) agg4[j] = make_float4(0.f, 0.f, 0.f, 0.f);
    for (int j = i; j < n; j += stride) deg[j] = 0.f;
}

// ---------------- edge scatter: agg[dst] += x[src]; deg[dst] += 1 ----------------
__global__ __launch_bounds__(256) void scatter_kernel(
        const float* __restrict__ x, const int* __restrict__ src,
        const int* __restrict__ dst, float* __restrict__ agg,
        float* __restrict__ deg, int n_edges) {
    int sub  = threadIdx.x >> 5;          // 8 edges per block
    int lane = threadIdx.x & 31;          // 32 lanes per edge, float4 each
    int e = blockIdx.x * 8 + sub;
    if (e >= n_edges) return;
    int s = src[e];
    int d = dst[e];
    float4 v = ((const float4*)(x + (size_t)s * F))[lane];
    float* a = agg + (size_t)d * F + lane * 4;
    atomicAdd(a + 0, v.x);
    atomicAdd(a + 1, v.y);
    atomicAdd(a + 2, v.z);
    atomicAdd(a + 3, v.w);
    if (lane == 0) atomicAdd(deg + d, 1.0f);
}

// ---------------- fused GEMM: out = relu(x@Ws + (agg/max(deg,1))@Wn + b) ----------------
__device__ __forceinline__ float4 f4fma(float4 a, float s, float4 c) {
    c.x = fmaf(a.x, s, c.x);
    c.y = fmaf(a.y, s, c.y);
    c.z = fmaf(a.z, s, c.z);
    c.w = fmaf(a.w, s, c.w);
    return c;
}

__global__ __launch_bounds__(256) void gemm_kernel(
        const float* __restrict__ x, const float* __restrict__ agg,
        const float* __restrict__ deg, const float* __restrict__ Ws,
        const float* __restrict__ Wn, const float* __restrict__ b,
        float* __restrict__ out, int n) {
    __shared__ __align__(16) float xs[TN][F];
    __shared__ __align__(16) float hs[TN][F];

    int v0  = blockIdx.x * TN;
    int tid = threadIdx.x;

    // stage x tile and h = agg/max(deg,1) tile into LDS (2048 float4 slots, 8/thread)
    #pragma unroll
    for (int j = 0; j < 8; ++j) {
        int idx = tid + 256 * j;      // [0, 2048)
        int row = idx >> 5;
        int c4  = idx & 31;
        int v   = v0 + row;
        float4 xv = make_float4(0.f, 0.f, 0.f, 0.f);
        float4 hv = xv;
        if (v < n) {
            xv = ((const float4*)(x + (size_t)v * F))[c4];
            float r = 1.0f / fmaxf(deg[v], 1.0f);
            float4 av = ((const float4*)(agg + (size_t)v * F))[c4];
            hv = make_float4(av.x * r, av.y * r, av.z * r, av.w * r);
        }
        ((float4*)&xs[row][0])[c4] = xv;
        ((float4*)&hs[row][0])[c4] = hv;
    }
    __syncthreads();

    int tx = tid & 31;   // f4 column group: features tx*4 .. tx*4+3
    int ty = tid >> 5;   // 0..7, node sub-row

    float4 acc[8];
    #pragma unroll
    for (int i = 0; i < 8; ++i) acc[i] = make_float4(0.f, 0.f, 0.f, 0.f);

    const float4* Ws4 = (const float4*)Ws;
    const float4* Wn4 = (const float4*)Wn;

    for (int k = 0; k < F; k += 4) {
        float4 ws[4], wn[4];
        #pragma unroll
        for (int kk = 0; kk < 4; ++kk) {
            ws[kk] = Ws4[(k + kk) * F4 + tx];
            wn[kk] = Wn4[(k + kk) * F4 + tx];
        }
        #pragma unroll
        for (int i = 0; i < 8; ++i) {
            int r = ty + 8 * i;
            float4 xv = *(const float4*)&xs[r][k];
            float4 hv = *(const float4*)&hs[r][k];
            acc[i] = f4fma(ws[0], xv.x, acc[i]);
            acc[i] = f4fma(wn[0], hv.x, acc[i]);
            acc[i] = f4fma(ws[1], xv.y, acc[i]);
            acc[i] = f4fma(wn[1], hv.y, acc[i]);
            acc[i] = f4fma(ws[2], xv.z, acc[i]);
            acc[i] = f4fma(wn[2], hv.z, acc[i]);
            acc[i] = f4fma(ws[3], xv.w, acc[i]);
            acc[i] = f4fma(wn[3], hv.w, acc[i]);
        }
    }

    float4 bb = ((const float4*)b)[tx];
    #pragma unroll
    for (int i = 0; i < 8; ++i) {
        int v = v0 + ty + 8 * i;
        if (v < n) {
            float4 r;
            r.x = fmaxf(acc[i].x + bb.x, 0.f);
            r.y = fmaxf(acc[i].y + bb.y, 0.f);
            r.z = fmaxf(acc[i].z + bb.z, 0.f);
            r.w = fmaxf(acc[i].w + bb.w, 0.f);
            ((float4*)(out + (size_t)v * F))[tx] = r;
        }
    }
}

extern "C" void kernel_launch(void* const* d_in, const int* in_sizes, int n_in,
                              void* d_out, int out_size, void* d_ws, size_t ws_size,
                              hipStream_t stream) {
    const float* x  = (const float*)d_in[0];
    const float* Ws = (const float*)d_in[1];
    const float* Wn = (const float*)d_in[2];
    const float* b  = (const float*)d_in[3];
    const int* src  = (const int*)d_in[4];
    const int* dst  = (const int*)d_in[5];
    int n = in_sizes[0] / F;      // 50000
    int E = in_sizes[4];          // 600000

    float* agg = (float*)d_ws;                 // n*F floats
    float* deg = agg + (size_t)n * F;          // n floats
    float* out = (float*)d_out;

    zero_kernel<<<1024, 256, 0, stream>>>((float4*)agg, deg, n);
    scatter_kernel<<<(E + 7) / 8, 256, 0, stream>>>(x, src, dst, agg, deg, E);
    gemm_kernel<<<(n + TN - 1) / TN, 256, 0, stream>>>(x, agg, deg, Ws, Wn, b, out, n);
}

// Round 2
// 336.726 us; speedup vs baseline: 3.4983x; 3.4983x over previous
//
#include <hip/hip_runtime.h>

#define F 128
#define F4 32   // float4 per row
#define TN 64   // nodes per GEMM block

// ---------------- zero counts ----------------
__global__ void zero_counts_kernel(int* __restrict__ counts, int n) {
    int i = blockIdx.x * blockDim.x + threadIdx.x;
    if (i < n) counts[i] = 0;
}

// ---------------- histogram of dst ----------------
__global__ __launch_bounds__(256) void hist_kernel(const int* __restrict__ dst,
                                                   int* __restrict__ counts, int E) {
    int e = blockIdx.x * blockDim.x + threadIdx.x;
    if (e < E) atomicAdd(&counts[dst[e]], 1);
}

// ---------------- exclusive scan (single block, 1024 threads) ----------------
__global__ __launch_bounds__(1024) void scan_kernel(const int* __restrict__ counts,
                                                    int* __restrict__ offsets,
                                                    int* __restrict__ cursor, int n) {
    __shared__ int smem[1024];
    __shared__ int carry;
    int tid = threadIdx.x;
    if (tid == 0) carry = 0;
    __syncthreads();
    for (int base = 0; base < n; base += 1024) {
        int i = base + tid;
        int v = (i < n) ? counts[i] : 0;
        smem[tid] = v;
        __syncthreads();
        #pragma unroll
        for (int off = 1; off < 1024; off <<= 1) {
            int t = (tid >= off) ? smem[tid - off] : 0;
            __syncthreads();
            smem[tid] += t;
            __syncthreads();
        }
        int c = carry;                 // stable: last write was before a barrier
        int incl = smem[tid];
        int excl = incl - v + c;
        if (i < n) { offsets[i] = excl; cursor[i] = excl; }
        __syncthreads();               // everyone done reading carry & smem
        if (tid == 0) carry = c + smem[1023];
        __syncthreads();
    }
    if (tid == 0) offsets[n] = carry;  // == E
}

// ---------------- fill CSR buckets ----------------
__global__ __launch_bounds__(256) void fill_kernel(const int* __restrict__ src,
                                                   const int* __restrict__ dst,
                                                   int* __restrict__ cursor,
                                                   int* __restrict__ esrc, int E) {
    int e = blockIdx.x * blockDim.x + threadIdx.x;
    if (e < E) {
        int p = atomicAdd(&cursor[dst[e]], 1);
        esrc[p] = src[e];
    }
}

// ---------------- gather-aggregate: h[v] = mean_{u->v} x[u] ----------------
__global__ __launch_bounds__(256) void agg_kernel(const float* __restrict__ x,
                                                  const int* __restrict__ esrc,
                                                  const int* __restrict__ offsets,
                                                  float* __restrict__ h, int n) {
    int half = threadIdx.x >> 5;       // 8 nodes per block
    int lane = threadIdx.x & 31;       // 32 lanes x float4 = 128 floats
    int v = blockIdx.x * 8 + half;
    if (v >= n) return;
    int beg = offsets[v];
    int end = offsets[v + 1];
    float4 acc = make_float4(0.f, 0.f, 0.f, 0.f);
    for (int j = beg; j < end; ++j) {
        int s = esrc[j];               // broadcast across the 32 lanes
        float4 xv = ((const float4*)(x + (size_t)s * F))[lane];
        acc.x += xv.x; acc.y += xv.y; acc.z += xv.z; acc.w += xv.w;
    }
    float r = (end > beg) ? 1.0f / (float)(end - beg) : 0.f;
    acc.x *= r; acc.y *= r; acc.z *= r; acc.w *= r;
    ((float4*)(h + (size_t)v * F))[lane] = acc;
}

// ---------------- fused GEMM: out = relu(x@Ws + h@Wn + b) ----------------
__device__ __forceinline__ float4 f4fma(float4 a, float s, float4 c) {
    c.x = fmaf(a.x, s, c.x);
    c.y = fmaf(a.y, s, c.y);
    c.z = fmaf(a.z, s, c.z);
    c.w = fmaf(a.w, s, c.w);
    return c;
}

__global__ __launch_bounds__(256) void gemm_kernel(
        const float* __restrict__ x, const float* __restrict__ h,
        const float* __restrict__ Ws, const float* __restrict__ Wn,
        const float* __restrict__ b, float* __restrict__ out, int n) {
    __shared__ __align__(16) float xs[TN][F];
    __shared__ __align__(16) float hs[TN][F];

    int v0  = blockIdx.x * TN;
    int tid = threadIdx.x;

    #pragma unroll
    for (int j = 0; j < 8; ++j) {
        int idx = tid + 256 * j;      // [0, 2048)
        int row = idx >> 5;
        int c4  = idx & 31;
        int v   = v0 + row;
        float4 xv = make_float4(0.f, 0.f, 0.f, 0.f);
        float4 hv = xv;
        if (v < n) {
            xv = ((const float4*)(x + (size_t)v * F))[c4];
            hv = ((const float4*)(h + (size_t)v * F))[c4];
        }
        ((float4*)&xs[row][0])[c4] = xv;
        ((float4*)&hs[row][0])[c4] = hv;
    }
    __syncthreads();

    int tx = tid & 31;   // feature group tx*4..tx*4+3
    int ty = tid >> 5;   // 0..7

    float4 acc[8];
    #pragma unroll
    for (int i = 0; i < 8; ++i) acc[i] = make_float4(0.f, 0.f, 0.f, 0.f);

    const float4* Ws4 = (const float4*)Ws;
    const float4* Wn4 = (const float4*)Wn;

    for (int k = 0; k < F; k += 4) {
        float4 ws[4], wn[4];
        #pragma unroll
        for (int kk = 0; kk < 4; ++kk) {
            ws[kk] = Ws4[(k + kk) * F4 + tx];
            wn[kk] = Wn4[(k + kk) * F4 + tx];
        }
        #pragma unroll
        for (int i = 0; i < 8; ++i) {
            int r = ty + 8 * i;
            float4 xv = *(const float4*)&xs[r][k];
            float4 hv = *(const float4*)&hs[r][k];
            acc[i] = f4fma(ws[0], xv.x, acc[i]);
            acc[i] = f4fma(wn[0], hv.x, acc[i]);
            acc[i] = f4fma(ws[1], xv.y, acc[i]);
            acc[i] = f4fma(wn[1], hv.y, acc[i]);
            acc[i] = f4fma(ws[2], xv.z, acc[i]);
            acc[i] = f4fma(wn[2], hv.z, acc[i]);
            acc[i] = f4fma(ws[3], xv.w, acc[i]);
            acc[i] = f4fma(wn[3], hv.w, acc[i]);
        }
    }

    float4 bb = ((const float4*)b)[tx];
    #pragma unroll
    for (int i = 0; i < 8; ++i) {
        int v = v0 + ty + 8 * i;
        if (v < n) {
            float4 r;
            r.x = fmaxf(acc[i].x + bb.x, 0.f);
            r.y = fmaxf(acc[i].y + bb.y, 0.f);
            r.z = fmaxf(acc[i].z + bb.z, 0.f);
            r.w = fmaxf(acc[i].w + bb.w, 0.f);
            ((float4*)(out + (size_t)v * F))[tx] = r;
        }
    }
}

extern "C" void kernel_launch(void* const* d_in, const int* in_sizes, int n_in,
                              void* d_out, int out_size, void* d_ws, size_t ws_size,
                              hipStream_t stream) {
    const float* x  = (const float*)d_in[0];
    const float* Ws = (const float*)d_in[1];
    const float* Wn = (const float*)d_in[2];
    const float* b  = (const float*)d_in[3];
    const int* src  = (const int*)d_in[4];
    const int* dst  = (const int*)d_in[5];
    int n = in_sizes[0] / F;      // 50000
    int E = in_sizes[4];          // 600000

    // workspace layout (floats/ints are both 4B):
    //   h       : n*F floats              (25.6 MB)
    //   counts  : n ints
    //   offsets : n+1 ints
    //   cursor  : n ints
    //   esrc    : E ints                  (~2.4 MB)
    float* h      = (float*)d_ws;
    int*  counts  = (int*)(h + (size_t)n * F);
    int*  offsets = counts + n;
    int*  cursor  = offsets + (n + 1);
    int*  esrc    = cursor + n;

    float* out = (float*)d_out;

    zero_counts_kernel<<<(n + 255) / 256, 256, 0, stream>>>(counts, n);
    hist_kernel<<<(E + 255) / 256, 256, 0, stream>>>(dst, counts, E);
    scan_kernel<<<1, 1024, 0, stream>>>(counts, offsets, cursor, n);
    fill_kernel<<<(E + 255) / 256, 256, 0, stream>>>(src, dst, cursor, esrc, E);
    agg_kernel<<<(n + 7) / 8, 256, 0, stream>>>(x, esrc, offsets, h, n);
    gemm_kernel<<<(n + TN - 1) / TN, 256, 0, stream>>>(x, h, Ws, Wn, b, out, n);
}

// Round 3
// 255.176 us; speedup vs baseline: 4.6163x; 1.3196x over previous
//
#include <hip/hip_runtime.h>

#define F 128
#define F4 32   // float4 per row
#define TN 64   // nodes per GEMM block

// ---------------- zero counts ----------------
__global__ void zero_counts_kernel(int* __restrict__ counts, int n) {
    int i = blockIdx.x * blockDim.x + threadIdx.x;
    if (i < n) counts[i] = 0;
}

// ---------------- histogram of dst ----------------
__global__ __launch_bounds__(256) void hist_kernel(const int* __restrict__ dst,
                                                   int* __restrict__ counts, int E) {
    int e = blockIdx.x * blockDim.x + threadIdx.x;
    if (e < E) atomicAdd(&counts[dst[e]], 1);
}

// ---------------- 3-phase exclusive scan ----------------
// phase 1: per-block (1024 elems) exclusive scan + block sums
__global__ __launch_bounds__(256) void scan_local_kernel(const int* __restrict__ counts,
                                                         int* __restrict__ offsets,
                                                         int* __restrict__ bsums, int n) {
    __shared__ int wsum[4];
    int tid = threadIdx.x;
    int base = blockIdx.x * 1024 + tid * 4;
    int4 c = make_int4(0, 0, 0, 0);
    if (base + 3 < n) c = *(const int4*)(counts + base);
    else if (base < n) {
        c.x = counts[base];
        if (base + 1 < n) c.y = counts[base + 1];
        if (base + 2 < n) c.z = counts[base + 2];
    }
    int tsum = c.x + c.y + c.z + c.w;
    int lane = tid & 63, wid = tid >> 6;
    int v = tsum;
    #pragma unroll
    for (int off = 1; off < 64; off <<= 1) {
        int t = __shfl_up(v, off);
        if (lane >= off) v += t;
    }
    if (lane == 63) wsum[wid] = v;
    __syncthreads();
    int wexcl = 0;
    #pragma unroll
    for (int w = 0; w < 3; ++w) if (w < wid) wexcl += wsum[w];
    int texcl = wexcl + v - tsum;   // exclusive prefix of this thread's 4 elems
    int4 o;
    o.x = texcl;
    o.y = o.x + c.x;
    o.z = o.y + c.y;
    o.w = o.z + c.z;
    if (base + 3 < n) *(int4*)(offsets + base) = o;
    else if (base < n) {
        offsets[base] = o.x;
        if (base + 1 < n) offsets[base + 1] = o.y;
        if (base + 2 < n) offsets[base + 2] = o.z;
    }
    if (tid == 255) bsums[blockIdx.x] = wexcl + v;   // block total
}

// phase 2: exclusive scan of block sums (single wave, loops if nb > 64)
__global__ __launch_bounds__(64) void scan_bsums_kernel(int* __restrict__ bsums,
                                                        int* __restrict__ offsets,
                                                        int nb, int n) {
    int lane = threadIdx.x;
    int carry = 0;
    for (int base = 0; base < nb; base += 64) {
        int i = base + lane;
        int orig = (i < nb) ? bsums[i] : 0;
        int v = orig;
        #pragma unroll
        for (int off = 1; off < 64; off <<= 1) {
            int t = __shfl_up(v, off);
            if (lane >= off) v += t;
        }
        if (i < nb) bsums[i] = carry + v - orig;   // exclusive
        carry += __shfl(v, 63);
    }
    if (lane == 0) offsets[n] = carry;   // == E
}

// phase 3: add block offsets, write final offsets + cursor copy
__global__ __launch_bounds__(256) void scan_add_kernel(int* __restrict__ offsets,
                                                       const int* __restrict__ bsums,
                                                       int* __restrict__ cursor, int n) {
    int base = (blockIdx.x * 256 + threadIdx.x) * 4;
    if (base >= n) return;
    int boff = bsums[base >> 10];
    if (base + 3 < n) {
        int4 v = *(const int4*)(offsets + base);
        v.x += boff; v.y += boff; v.z += boff; v.w += boff;
        *(int4*)(offsets + base) = v;
        *(int4*)(cursor + base) = v;
    } else {
        for (int j = 0; j < 4 && base + j < n; ++j) {
            int v = offsets[base + j] + boff;
            offsets[base + j] = v;
            cursor[base + j] = v;
        }
    }
}

// ---------------- fill CSR buckets ----------------
__global__ __launch_bounds__(256) void fill_kernel(const int* __restrict__ src,
                                                   const int* __restrict__ dst,
                                                   int* __restrict__ cursor,
                                                   int* __restrict__ esrc, int E) {
    int e = blockIdx.x * blockDim.x + threadIdx.x;
    if (e < E) {
        int p = atomicAdd(&cursor[dst[e]], 1);
        esrc[p] = src[e];
    }
}

// ---------------- gather-aggregate: h[v] = mean_{u->v} x[u] ----------------
__global__ __launch_bounds__(256) void agg_kernel(const float* __restrict__ x,
                                                  const int* __restrict__ esrc,
                                                  const int* __restrict__ offsets,
                                                  float* __restrict__ h, int n) {
    int half = threadIdx.x >> 5;       // 8 nodes per block
    int lane = threadIdx.x & 31;       // 32 lanes x float4 = 128 floats
    int v = blockIdx.x * 8 + half;
    if (v >= n) return;
    int beg = offsets[v];
    int end = offsets[v + 1];
    float4 acc = make_float4(0.f, 0.f, 0.f, 0.f);
    for (int j = beg; j < end; ++j) {
        int s = esrc[j];               // broadcast across the 32 lanes
        float4 xv = ((const float4*)(x + (size_t)s * F))[lane];
        acc.x += xv.x; acc.y += xv.y; acc.z += xv.z; acc.w += xv.w;
    }
    float r = (end > beg) ? 1.0f / (float)(end - beg) : 0.f;
    acc.x *= r; acc.y *= r; acc.z *= r; acc.w *= r;
    ((float4*)(h + (size_t)v * F))[lane] = acc;
}

// ---------------- fused GEMM: out = relu(x@Ws + h@Wn + b) ----------------
__device__ __forceinline__ float4 f4fma(float4 a, float s, float4 c) {
    c.x = fmaf(a.x, s, c.x);
    c.y = fmaf(a.y, s, c.y);
    c.z = fmaf(a.z, s, c.z);
    c.w = fmaf(a.w, s, c.w);
    return c;
}

__global__ __launch_bounds__(256) void gemm_kernel(
        const float* __restrict__ x, const float* __restrict__ h,
        const float* __restrict__ Ws, const float* __restrict__ Wn,
        const float* __restrict__ b, float* __restrict__ out, int n) {
    __shared__ __align__(16) float xs[TN][F];
    __shared__ __align__(16) float hs[TN][F];

    int v0  = blockIdx.x * TN;
    int tid = threadIdx.x;

    #pragma unroll
    for (int j = 0; j < 8; ++j) {
        int idx = tid + 256 * j;      // [0, 2048)
        int row = idx >> 5;
        int c4  = idx & 31;
        int v   = v0 + row;
        float4 xv = make_float4(0.f, 0.f, 0.f, 0.f);
        float4 hv = xv;
        if (v < n) {
            xv = ((const float4*)(x + (size_t)v * F))[c4];
            hv = ((const float4*)(h + (size_t)v * F))[c4];
        }
        ((float4*)&xs[row][0])[c4] = xv;
        ((float4*)&hs[row][0])[c4] = hv;
    }
    __syncthreads();

    int tx = tid & 31;   // feature group tx*4..tx*4+3
    int ty = tid >> 5;   // 0..7

    float4 acc[8];
    #pragma unroll
    for (int i = 0; i < 8; ++i) acc[i] = make_float4(0.f, 0.f, 0.f, 0.f);

    const float4* Ws4 = (const float4*)Ws;
    const float4* Wn4 = (const float4*)Wn;

    for (int k = 0; k < F; k += 4) {
        float4 ws[4], wn[4];
        #pragma unroll
        for (int kk = 0; kk < 4; ++kk) {
            ws[kk] = Ws4[(k + kk) * F4 + tx];
            wn[kk] = Wn4[(k + kk) * F4 + tx];
        }
        #pragma unroll
        for (int i = 0; i < 8; ++i) {
            int r = ty + 8 * i;
            float4 xv = *(const float4*)&xs[r][k];
            float4 hv = *(const float4*)&hs[r][k];
            acc[i] = f4fma(ws[0], xv.x, acc[i]);
            acc[i] = f4fma(wn[0], hv.x, acc[i]);
            acc[i] = f4fma(ws[1], xv.y, acc[i]);
            acc[i] = f4fma(wn[1], hv.y, acc[i]);
            acc[i] = f4fma(ws[2], xv.z, acc[i]);
            acc[i] = f4fma(wn[2], hv.z, acc[i]);
            acc[i] = f4fma(ws[3], xv.w, acc[i]);
            acc[i] = f4fma(wn[3], hv.w, acc[i]);
        }
    }

    float4 bb = ((const float4*)b)[tx];
    #pragma unroll
    for (int i = 0; i < 8; ++i) {
        int v = v0 + ty + 8 * i;
        if (v < n) {
            float4 r;
            r.x = fmaxf(acc[i].x + bb.x, 0.f);
            r.y = fmaxf(acc[i].y + bb.y, 0.f);
            r.z = fmaxf(acc[i].z + bb.z, 0.f);
            r.w = fmaxf(acc[i].w + bb.w, 0.f);
            ((float4*)(out + (size_t)v * F))[tx] = r;
        }
    }
}

extern "C" void kernel_launch(void* const* d_in, const int* in_sizes, int n_in,
                              void* d_out, int out_size, void* d_ws, size_t ws_size,
                              hipStream_t stream) {
    const float* x  = (const float*)d_in[0];
    const float* Ws = (const float*)d_in[1];
    const float* Wn = (const float*)d_in[2];
    const float* b  = (const float*)d_in[3];
    const int* src  = (const int*)d_in[4];
    const int* dst  = (const int*)d_in[5];
    int n = in_sizes[0] / F;      // 50000
    int E = in_sizes[4];          // 600000

    int nb = (n + 1023) / 1024;   // scan blocks (49)

    // workspace layout (all 4B elems):
    //   h       : n*F floats
    //   counts  : n ints
    //   offsets : n+1 ints
    //   cursor  : n ints
    //   esrc    : E ints
    //   bsums   : nb ints
    float* h      = (float*)d_ws;
    int*  counts  = (int*)(h + (size_t)n * F);
    int*  offsets = counts + n;
    int*  cursor  = offsets + (n + 1);
    int*  esrc    = cursor + n;
    int*  bsums   = esrc + E;

    float* out = (float*)d_out;

    zero_counts_kernel<<<(n + 255) / 256, 256, 0, stream>>>(counts, n);
    hist_kernel<<<(E + 255) / 256, 256, 0, stream>>>(dst, counts, E);
    scan_local_kernel<<<nb, 256, 0, stream>>>(counts, offsets, bsums, n);
    scan_bsums_kernel<<<1, 64, 0, stream>>>(bsums, offsets, nb, n);
    scan_add_kernel<<<(n / 4 + 255) / 256, 256, 0, stream>>>(offsets, bsums, cursor, n);
    fill_kernel<<<(E + 255) / 256, 256, 0, stream>>>(src, dst, cursor, esrc, E);
    agg_kernel<<<(n + 7) / 8, 256, 0, stream>>>(x, esrc, offsets, h, n);
    gemm_kernel<<<(n + TN - 1) / TN, 256, 0, stream>>>(x, h, Ws, Wn, b, out, n);
}

// Round 4
// 222.649 us; speedup vs baseline: 5.2907x; 1.1461x over previous
//
#include <hip/hip_runtime.h>

#define F 128

typedef short bf16x8 __attribute__((ext_vector_type(8)));   // 8 bf16 = 4 VGPRs
typedef float f32x4  __attribute__((ext_vector_type(4)));

__device__ __forceinline__ unsigned short f2bf(float f) {
    unsigned int u = __float_as_uint(f);
    u += 0x7fffu + ((u >> 16) & 1u);        // round-to-nearest-even
    return (unsigned short)(u >> 16);
}

// ---------------- zero counts ----------------
__global__ void zero_counts_kernel(int* __restrict__ counts, int n) {
    int i = blockIdx.x * blockDim.x + threadIdx.x;
    if (i < n) counts[i] = 0;
}

// ---------------- histogram of dst ----------------
__global__ __launch_bounds__(256) void hist_kernel(const int* __restrict__ dst,
                                                   int* __restrict__ counts, int E) {
    int e = blockIdx.x * blockDim.x + threadIdx.x;
    if (e < E) atomicAdd(&counts[dst[e]], 1);
}

// ---------------- 3-phase exclusive scan ----------------
__global__ __launch_bounds__(256) void scan_local_kernel(const int* __restrict__ counts,
                                                         int* __restrict__ offsets,
                                                         int* __restrict__ bsums, int n) {
    __shared__ int wsum[4];
    int tid = threadIdx.x;
    int base = blockIdx.x * 1024 + tid * 4;
    int4 c = make_int4(0, 0, 0, 0);
    if (base + 3 < n) c = *(const int4*)(counts + base);
    else if (base < n) {
        c.x = counts[base];
        if (base + 1 < n) c.y = counts[base + 1];
        if (base + 2 < n) c.z = counts[base + 2];
    }
    int tsum = c.x + c.y + c.z + c.w;
    int lane = tid & 63, wid = tid >> 6;
    int v = tsum;
    #pragma unroll
    for (int off = 1; off < 64; off <<= 1) {
        int t = __shfl_up(v, off);
        if (lane >= off) v += t;
    }
    if (lane == 63) wsum[wid] = v;
    __syncthreads();
    int wexcl = 0;
    #pragma unroll
    for (int w = 0; w < 3; ++w) if (w < wid) wexcl += wsum[w];
    int texcl = wexcl + v - tsum;
    int4 o;
    o.x = texcl;
    o.y = o.x + c.x;
    o.z = o.y + c.y;
    o.w = o.z + c.z;
    if (base + 3 < n) *(int4*)(offsets + base) = o;
    else if (base < n) {
        offsets[base] = o.x;
        if (base + 1 < n) offsets[base + 1] = o.y;
        if (base + 2 < n) offsets[base + 2] = o.z;
    }
    if (tid == 255) bsums[blockIdx.x] = wexcl + v;
}

__global__ __launch_bounds__(64) void scan_bsums_kernel(int* __restrict__ bsums,
                                                        int* __restrict__ offsets,
                                                        int nb, int n) {
    int lane = threadIdx.x;
    int carry = 0;
    for (int base = 0; base < nb; base += 64) {
        int i = base + lane;
        int orig = (i < nb) ? bsums[i] : 0;
        int v = orig;
        #pragma unroll
        for (int off = 1; off < 64; off <<= 1) {
            int t = __shfl_up(v, off);
            if (lane >= off) v += t;
        }
        if (i < nb) bsums[i] = carry + v - orig;
        carry += __shfl(v, 63);
    }
    if (lane == 0) offsets[n] = carry;
}

__global__ __launch_bounds__(256) void scan_add_kernel(int* __restrict__ offsets,
                                                       const int* __restrict__ bsums,
                                                       int* __restrict__ cursor, int n) {
    int base = (blockIdx.x * 256 + threadIdx.x) * 4;
    if (base >= n) return;
    int boff = bsums[base >> 10];
    if (base + 3 < n) {
        int4 v = *(const int4*)(offsets + base);
        v.x += boff; v.y += boff; v.z += boff; v.w += boff;
        *(int4*)(offsets + base) = v;
        *(int4*)(cursor + base) = v;
    } else {
        for (int j = 0; j < 4 && base + j < n; ++j) {
            int v = offsets[base + j] + boff;
            offsets[base + j] = v;
            cursor[base + j] = v;
        }
    }
}

// ---------------- fill CSR buckets ----------------
__global__ __launch_bounds__(256) void fill_kernel(const int* __restrict__ src,
                                                   const int* __restrict__ dst,
                                                   int* __restrict__ cursor,
                                                   int* __restrict__ esrc, int E) {
    int e = blockIdx.x * blockDim.x + threadIdx.x;
    if (e < E) {
        int p = atomicAdd(&cursor[dst[e]], 1);
        esrc[p] = src[e];
    }
}

// ---------------- convert x fp32 -> bf16 into xh[:, 0:128] ----------------
__global__ __launch_bounds__(256) void convert_x_kernel(const float* __restrict__ x,
                                                        unsigned short* __restrict__ xh,
                                                        int n) {
    int gid = blockIdx.x * 256 + threadIdx.x;   // one thread per 8 floats
    int total = n * 16;
    if (gid >= total) return;
    int node = gid >> 4;
    int c = (gid & 15) * 8;
    const float4* p = (const float4*)(x + (size_t)node * F + c);
    float4 v0 = p[0], v1 = p[1];
    bf16x8 o;
    o[0] = (short)f2bf(v0.x); o[1] = (short)f2bf(v0.y);
    o[2] = (short)f2bf(v0.z); o[3] = (short)f2bf(v0.w);
    o[4] = (short)f2bf(v1.x); o[5] = (short)f2bf(v1.y);
    o[6] = (short)f2bf(v1.z); o[7] = (short)f2bf(v1.w);
    *(bf16x8*)(xh + (size_t)node * 256 + c) = o;
}

// ---------------- pack [Ws;Wn] into MFMA B-fragment order (bf16) ----------------
// Bpack[((s*8 + t)*64 + lane)*8 + j] = W[k=s*32+(lane>>4)*8+j][col=t*16+(lane&15)]
__global__ __launch_bounds__(256) void pack_w_kernel(const float* __restrict__ Ws,
                                                     const float* __restrict__ Wn,
                                                     unsigned short* __restrict__ Bpack) {
    int idx = blockIdx.x * 256 + threadIdx.x;   // 0..32767
    int j    = idx & 7;
    int lane = (idx >> 3) & 63;
    int tile = idx >> 9;        // 0..63
    int s = tile >> 3;
    int t = tile & 7;
    int k = s * 32 + (lane >> 4) * 8 + j;
    int c = t * 16 + (lane & 15);
    float v = (k < F) ? Ws[k * F + c] : Wn[(k - F) * F + c];
    Bpack[idx] = f2bf(v);
}

// ---------------- gather-aggregate: xh[v, 128:256] = bf16(mean_{u->v} x[u]) ----------------
__global__ __launch_bounds__(256) void agg_kernel(const float* __restrict__ x,
                                                  const int* __restrict__ esrc,
                                                  const int* __restrict__ offsets,
                                                  unsigned short* __restrict__ xh, int n) {
    int half = threadIdx.x >> 5;       // 8 nodes per block
    int lane = threadIdx.x & 31;       // 32 lanes x float4 = 128 floats
    int v = blockIdx.x * 8 + half;
    if (v >= n) return;
    int beg = offsets[v];
    int end = offsets[v + 1];
    float4 acc = make_float4(0.f, 0.f, 0.f, 0.f);
    for (int j = beg; j < end; ++j) {
        int s = esrc[j];
        float4 xv = ((const float4*)(x + (size_t)s * F))[lane];
        acc.x += xv.x; acc.y += xv.y; acc.z += xv.z; acc.w += xv.w;
    }
    float r = (end > beg) ? 1.0f / (float)(end - beg) : 0.f;
    ushort4 o;
    o.x = f2bf(acc.x * r); o.y = f2bf(acc.y * r);
    o.z = f2bf(acc.z * r); o.w = f2bf(acc.w * r);
    *(ushort4*)(xh + (size_t)v * 256 + 128 + lane * 4) = o;
}

// ---------------- MFMA GEMM: out = relu(xh @ Bpack + b), fp32 out ----------------
// block = 64 rows x 128 cols, 4 waves; wave = 32 rows x 64 cols
__global__ __launch_bounds__(256) void mfma_gemm_kernel(
        const unsigned short* __restrict__ xh,
        const unsigned short* __restrict__ Bpack,
        const float* __restrict__ bias,
        float* __restrict__ out, int n) {
    int wave = threadIdx.x >> 6;
    int lane = threadIdx.x & 63;
    int q = lane >> 4;
    int m = lane & 15;
    int rowhalf = (wave & 1) * 32;
    int coltile = (wave >> 1) * 4;              // first of 4 col-tiles
    int row0 = blockIdx.x * 64 + rowhalf;

    f32x4 acc[2][4];
    #pragma unroll
    for (int r = 0; r < 2; ++r)
        #pragma unroll
        for (int t = 0; t < 4; ++t) acc[r][t] = 0.f;

    int r0 = min(row0 + m, n - 1);
    int r1 = min(row0 + 16 + m, n - 1);
    const unsigned short* a0p = xh + (size_t)r0 * 256 + q * 8;
    const unsigned short* a1p = xh + (size_t)r1 * 256 + q * 8;

    #pragma unroll
    for (int s = 0; s < 8; ++s) {
        bf16x8 a0 = *(const bf16x8*)(a0p + s * 32);
        bf16x8 a1 = *(const bf16x8*)(a1p + s * 32);
        #pragma unroll
        for (int t = 0; t < 4; ++t) {
            bf16x8 bf = *(const bf16x8*)(Bpack + ((size_t)((s * 8 + coltile + t) * 64 + lane)) * 8);
            acc[0][t] = __builtin_amdgcn_mfma_f32_16x16x32_bf16(a0, bf, acc[0][t], 0, 0, 0);
            acc[1][t] = __builtin_amdgcn_mfma_f32_16x16x32_bf16(a1, bf, acc[1][t], 0, 0, 0);
        }
    }

    #pragma unroll
    for (int r = 0; r < 2; ++r)
        #pragma unroll
        for (int t = 0; t < 4; ++t) {
            int col = (coltile + t) * 16 + m;
            float bv = bias[col];
            #pragma unroll
            for (int g = 0; g < 4; ++g) {
                int row = row0 + r * 16 + q * 4 + g;
                if (row < n)
                    out[(size_t)row * F + col] = fmaxf(acc[r][t][g] + bv, 0.f);
            }
        }
}

extern "C" void kernel_launch(void* const* d_in, const int* in_sizes, int n_in,
                              void* d_out, int out_size, void* d_ws, size_t ws_size,
                              hipStream_t stream) {
    const float* x  = (const float*)d_in[0];
    const float* Ws = (const float*)d_in[1];
    const float* Wn = (const float*)d_in[2];
    const float* b  = (const float*)d_in[3];
    const int* src  = (const int*)d_in[4];
    const int* dst  = (const int*)d_in[5];
    int n = in_sizes[0] / F;      // 50000
    int E = in_sizes[4];          // 600000

    int nb = (n + 1023) / 1024;

    // workspace layout (4B elems):
    //   xh      : n*256 bf16 (x | h)      25.6 MB
    //   counts  : n ints   (aliased by Bpack after scan_local)
    //   offsets : n+1 ints
    //   cursor  : n ints
    //   esrc    : E ints
    //   bsums   : nb ints
    unsigned short* xh = (unsigned short*)d_ws;
    int* counts  = (int*)(xh + (size_t)n * 256);
    int* offsets = counts + n;
    int* cursor  = offsets + (n + 1);
    int* esrc    = cursor + n;
    int* bsums   = esrc + E;
    unsigned short* Bpack = (unsigned short*)counts;   // 64 KB, counts dead after scan_local

    float* out = (float*)d_out;

    zero_counts_kernel<<<(n + 255) / 256, 256, 0, stream>>>(counts, n);
    hist_kernel<<<(E + 255) / 256, 256, 0, stream>>>(dst, counts, E);
    scan_local_kernel<<<nb, 256, 0, stream>>>(counts, offsets, bsums, n);
    scan_bsums_kernel<<<1, 64, 0, stream>>>(bsums, offsets, nb, n);
    scan_add_kernel<<<(n / 4 + 255) / 256, 256, 0, stream>>>(offsets, bsums, cursor, n);
    pack_w_kernel<<<128, 256, 0, stream>>>(Ws, Wn, Bpack);
    convert_x_kernel<<<(n * 16 + 255) / 256, 256, 0, stream>>>(x, xh, n);
    fill_kernel<<<(E + 255) / 256, 256, 0, stream>>>(src, dst, cursor, esrc, E);
    agg_kernel<<<(n + 7) / 8, 256, 0, stream>>>(x, esrc, offsets, xh, n);
    mfma_gemm_kernel<<<(n + 63) / 64, 256, 0, stream>>>(xh, Bpack, b, out, n);
}

// Round 5
// 203.093 us; speedup vs baseline: 5.8002x; 1.0963x over previous
//
#include <hip/hip_runtime.h>

#define F 128

typedef short bf16x8 __attribute__((ext_vector_type(8)));   // 8 bf16 = 4 VGPRs
typedef float f32x4  __attribute__((ext_vector_type(4)));

__device__ __forceinline__ unsigned short f2bf(float f) {
    unsigned int u = __float_as_uint(f);
    u += 0x7fffu + ((u >> 16) & 1u);        // round-to-nearest-even
    return (unsigned short)(u >> 16);
}
__device__ __forceinline__ float bf2f(unsigned short s) {
    return __uint_as_float(((unsigned int)s) << 16);
}

// ---------------- zero counts ----------------
__global__ void zero_counts_kernel(int* __restrict__ counts, int n) {
    int i = blockIdx.x * blockDim.x + threadIdx.x;
    if (i < n) counts[i] = 0;
}

// ---------------- histogram of dst ----------------
__global__ __launch_bounds__(256) void hist_kernel(const int* __restrict__ dst,
                                                   int* __restrict__ counts, int E) {
    int e = blockIdx.x * blockDim.x + threadIdx.x;
    if (e < E) atomicAdd(&counts[dst[e]], 1);
}

// ---------------- 3-phase exclusive scan ----------------
__global__ __launch_bounds__(256) void scan_local_kernel(const int* __restrict__ counts,
                                                         int* __restrict__ offsets,
                                                         int* __restrict__ bsums, int n) {
    __shared__ int wsum[4];
    int tid = threadIdx.x;
    int base = blockIdx.x * 1024 + tid * 4;
    int4 c = make_int4(0, 0, 0, 0);
    if (base + 3 < n) c = *(const int4*)(counts + base);
    else if (base < n) {
        c.x = counts[base];
        if (base + 1 < n) c.y = counts[base + 1];
        if (base + 2 < n) c.z = counts[base + 2];
    }
    int tsum = c.x + c.y + c.z + c.w;
    int lane = tid & 63, wid = tid >> 6;
    int v = tsum;
    #pragma unroll
    for (int off = 1; off < 64; off <<= 1) {
        int t = __shfl_up(v, off);
        if (lane >= off) v += t;
    }
    if (lane == 63) wsum[wid] = v;
    __syncthreads();
    int wexcl = 0;
    #pragma unroll
    for (int w = 0; w < 3; ++w) if (w < wid) wexcl += wsum[w];
    int texcl = wexcl + v - tsum;
    int4 o;
    o.x = texcl;
    o.y = o.x + c.x;
    o.z = o.y + c.y;
    o.w = o.z + c.z;
    if (base + 3 < n) *(int4*)(offsets + base) = o;
    else if (base < n) {
        offsets[base] = o.x;
        if (base + 1 < n) offsets[base + 1] = o.y;
        if (base + 2 < n) offsets[base + 2] = o.z;
    }
    if (tid == 255) bsums[blockIdx.x] = wexcl + v;
}

__global__ __launch_bounds__(64) void scan_bsums_kernel(int* __restrict__ bsums,
                                                        int* __restrict__ offsets,
                                                        int nb, int n) {
    int lane = threadIdx.x;
    int carry = 0;
    for (int base = 0; base < nb; base += 64) {
        int i = base + lane;
        int orig = (i < nb) ? bsums[i] : 0;
        int v = orig;
        #pragma unroll
        for (int off = 1; off < 64; off <<= 1) {
            int t = __shfl_up(v, off);
            if (lane >= off) v += t;
        }
        if (i < nb) bsums[i] = carry + v - orig;
        carry += __shfl(v, 63);
    }
    if (lane == 0) offsets[n] = carry;
}

__global__ __launch_bounds__(256) void scan_add_kernel(int* __restrict__ offsets,
                                                       const int* __restrict__ bsums,
                                                       int* __restrict__ cursor, int n) {
    int base = (blockIdx.x * 256 + threadIdx.x) * 4;
    if (base >= n) return;
    int boff = bsums[base >> 10];
    if (base + 3 < n) {
        int4 v = *(const int4*)(offsets + base);
        v.x += boff; v.y += boff; v.z += boff; v.w += boff;
        *(int4*)(offsets + base) = v;
        *(int4*)(cursor + base) = v;
    } else {
        for (int j = 0; j < 4 && base + j < n; ++j) {
            int v = offsets[base + j] + boff;
            offsets[base + j] = v;
            cursor[base + j] = v;
        }
    }
}

// ---------------- fill CSR buckets ----------------
__global__ __launch_bounds__(256) void fill_kernel(const int* __restrict__ src,
                                                   const int* __restrict__ dst,
                                                   int* __restrict__ cursor,
                                                   int* __restrict__ esrc, int E) {
    int e = blockIdx.x * blockDim.x + threadIdx.x;
    if (e < E) {
        int p = atomicAdd(&cursor[dst[e]], 1);
        esrc[p] = src[e];
    }
}

// ---------------- convert x fp32 -> bf16 into xh[:, 0:128] ----------------
__global__ __launch_bounds__(256) void convert_x_kernel(const float* __restrict__ x,
                                                        unsigned short* __restrict__ xh,
                                                        int n) {
    int gid = blockIdx.x * 256 + threadIdx.x;   // one thread per 8 floats
    int total = n * 16;
    if (gid >= total) return;
    int node = gid >> 4;
    int c = (gid & 15) * 8;
    const float4* p = (const float4*)(x + (size_t)node * F + c);
    float4 v0 = p[0], v1 = p[1];
    bf16x8 o;
    o[0] = (short)f2bf(v0.x); o[1] = (short)f2bf(v0.y);
    o[2] = (short)f2bf(v0.z); o[3] = (short)f2bf(v0.w);
    o[4] = (short)f2bf(v1.x); o[5] = (short)f2bf(v1.y);
    o[6] = (short)f2bf(v1.z); o[7] = (short)f2bf(v1.w);
    *(bf16x8*)(xh + (size_t)node * 256 + c) = o;
}

// ---------------- pack [Ws;Wn] into MFMA B-fragment order (bf16) ----------------
__global__ __launch_bounds__(256) void pack_w_kernel(const float* __restrict__ Ws,
                                                     const float* __restrict__ Wn,
                                                     unsigned short* __restrict__ Bpack) {
    int idx = blockIdx.x * 256 + threadIdx.x;   // 0..32767
    int j    = idx & 7;
    int lane = (idx >> 3) & 63;
    int tile = idx >> 9;        // 0..63
    int s = tile >> 3;
    int t = tile & 7;
    int k = s * 32 + (lane >> 4) * 8 + j;
    int c = t * 16 + (lane & 15);
    float v = (k < F) ? Ws[k * F + c] : Wn[(k - F) * F + c];
    Bpack[idx] = f2bf(v);
}

// ---------------- gather-aggregate (bf16 gather): xh[v,128:256] = bf16(mean x[u]) ----------------
__global__ __launch_bounds__(256) void agg_kernel(const int* __restrict__ esrc,
                                                  const int* __restrict__ offsets,
                                                  unsigned short* __restrict__ xh, int n) {
    int grp  = threadIdx.x >> 4;       // 16 nodes per block
    int lane = threadIdx.x & 15;       // 16 lanes x bf16x8 (16B) = 128 feats
    int v = blockIdx.x * 16 + grp;
    if (v >= n) return;
    int beg = offsets[v];
    int end = offsets[v + 1];
    float acc[8] = {0.f, 0.f, 0.f, 0.f, 0.f, 0.f, 0.f, 0.f};
    for (int j = beg; j < end; ++j) {
        int s = esrc[j];
        bf16x8 xv = *(const bf16x8*)(xh + (size_t)s * 256 + lane * 8);
        #pragma unroll
        for (int i = 0; i < 8; ++i)
            acc[i] += bf2f((unsigned short)xv[i]);
    }
    float r = (end > beg) ? 1.0f / (float)(end - beg) : 0.f;
    bf16x8 o;
    #pragma unroll
    for (int i = 0; i < 8; ++i) o[i] = (short)f2bf(acc[i] * r);
    *(bf16x8*)(xh + (size_t)v * 256 + 128 + lane * 8) = o;
}

// ---------------- MFMA GEMM: out = relu(xh @ Bpack + b), fp32 out ----------------
__global__ __launch_bounds__(256) void mfma_gemm_kernel(
        const unsigned short* __restrict__ xh,
        const unsigned short* __restrict__ Bpack,
        const float* __restrict__ bias,
        float* __restrict__ out, int n) {
    int wave = threadIdx.x >> 6;
    int lane = threadIdx.x & 63;
    int q = lane >> 4;
    int m = lane & 15;
    int rowhalf = (wave & 1) * 32;
    int coltile = (wave >> 1) * 4;
    int row0 = blockIdx.x * 64 + rowhalf;

    f32x4 acc[2][4];
    #pragma unroll
    for (int r = 0; r < 2; ++r)
        #pragma unroll
        for (int t = 0; t < 4; ++t) acc[r][t] = 0.f;

    int r0 = min(row0 + m, n - 1);
    int r1 = min(row0 + 16 + m, n - 1);
    const unsigned short* a0p = xh + (size_t)r0 * 256 + q * 8;
    const unsigned short* a1p = xh + (size_t)r1 * 256 + q * 8;

    #pragma unroll
    for (int s = 0; s < 8; ++s) {
        bf16x8 a0 = *(const bf16x8*)(a0p + s * 32);
        bf16x8 a1 = *(const bf16x8*)(a1p + s * 32);
        #pragma unroll
        for (int t = 0; t < 4; ++t) {
            bf16x8 bf = *(const bf16x8*)(Bpack + ((size_t)((s * 8 + coltile + t) * 64 + lane)) * 8);
            acc[0][t] = __builtin_amdgcn_mfma_f32_16x16x32_bf16(a0, bf, acc[0][t], 0, 0, 0);
            acc[1][t] = __builtin_amdgcn_mfma_f32_16x16x32_bf16(a1, bf, acc[1][t], 0, 0, 0);
        }
    }

    #pragma unroll
    for (int r = 0; r < 2; ++r)
        #pragma unroll
        for (int t = 0; t < 4; ++t) {
            int col = (coltile + t) * 16 + m;
            float bv = bias[col];
            #pragma unroll
            for (int g = 0; g < 4; ++g) {
                int row = row0 + r * 16 + q * 4 + g;
                if (row < n)
                    out[(size_t)row * F + col] = fmaxf(acc[r][t][g] + bv, 0.f);
            }
        }
}

extern "C" void kernel_launch(void* const* d_in, const int* in_sizes, int n_in,
                              void* d_out, int out_size, void* d_ws, size_t ws_size,
                              hipStream_t stream) {
    const float* x  = (const float*)d_in[0];
    const float* Ws = (const float*)d_in[1];
    const float* Wn = (const float*)d_in[2];
    const float* b  = (const float*)d_in[3];
    const int* src  = (const int*)d_in[4];
    const int* dst  = (const int*)d_in[5];
    int n = in_sizes[0] / F;      // 50000
    int E = in_sizes[4];          // 600000

    int nb = (n + 1023) / 1024;

    // workspace layout (4B elems):
    //   xh      : n*256 bf16 (x | h)      25.6 MB
    //   counts  : n ints   (aliased by Bpack after scan_local)
    //   offsets : n+1 ints
    //   cursor  : n ints
    //   esrc    : E ints
    //   bsums   : nb ints
    unsigned short* xh = (unsigned short*)d_ws;
    int* counts  = (int*)(xh + (size_t)n * 256);
    int* offsets = counts + n;
    int* cursor  = offsets + (n + 1);
    int* esrc    = cursor + n;
    int* bsums   = esrc + E;
    unsigned short* Bpack = (unsigned short*)counts;   // 64 KB, counts dead after scan_local

    float* out = (float*)d_out;

    zero_counts_kernel<<<(n + 255) / 256, 256, 0, stream>>>(counts, n);
    hist_kernel<<<(E + 255) / 256, 256, 0, stream>>>(dst, counts, E);
    scan_local_kernel<<<nb, 256, 0, stream>>>(counts, offsets, bsums, n);
    scan_bsums_kernel<<<1, 64, 0, stream>>>(bsums, offsets, nb, n);
    scan_add_kernel<<<(n / 4 + 255) / 256, 256, 0, stream>>>(offsets, bsums, cursor, n);
    pack_w_kernel<<<128, 256, 0, stream>>>(Ws, Wn, Bpack);
    convert_x_kernel<<<(n * 16 + 255) / 256, 256, 0, stream>>>(x, xh, n);
    fill_kernel<<<(E + 255) / 256, 256, 0, stream>>>(src, dst, cursor, esrc, E);
    agg_kernel<<<(n + 15) / 16, 256, 0, stream>>>(esrc, offsets, xh, n);
    mfma_gemm_kernel<<<(n + 63) / 64, 256, 0, stream>>>(xh, Bpack, b, out, n);
}